// Round 1
// 595.715 us; speedup vs baseline: 2.1441x; 2.1441x over previous
//
#include <hip/hip_runtime.h>

typedef __attribute__((ext_vector_type(8))) short s8v;
typedef __attribute__((ext_vector_type(4))) float f4v;

#define LOG2E 1.44269504088896340736f

__device__ __forceinline__ unsigned short f2bf(float f) {
    unsigned int x = __float_as_uint(f);
    return (unsigned short)((x + 0x7fffu + ((x >> 16) & 1u)) >> 16);
}
__device__ __forceinline__ s8v ld8(const unsigned short* p) {
    return *(const s8v*)p;
}
__device__ __forceinline__ s8v cvt8(const float* p) {
    f4v lo = *(const f4v*)p, hi = *(const f4v*)(p + 4);
    s8v r;
    r[0] = (short)f2bf(lo[0]); r[1] = (short)f2bf(lo[1]);
    r[2] = (short)f2bf(lo[2]); r[3] = (short)f2bf(lo[3]);
    r[4] = (short)f2bf(hi[0]); r[5] = (short)f2bf(hi[1]);
    r[6] = (short)f2bf(hi[2]); r[7] = (short)f2bf(hi[3]);
    return r;
}

// async global->LDS, 16B per lane; LDS dest is wave-uniform base + lane*16
#define GLOAD_LDS(g, l) __builtin_amdgcn_global_load_lds(              \
    (const __attribute__((address_space(1))) void*)(const void*)(g),   \
    (__attribute__((address_space(3))) void*)(void*)(l), 16, 0, 0)

// ------- W transpose + fp32->bf16: Wt[n][k] = bf16(W[k][n]), 1024x1024 -----
__global__ __launch_bounds__(256) void transpose_w(
    const float* __restrict__ W, unsigned short* __restrict__ Wt)
{
    __shared__ float tile[32][33];
    int tx = threadIdx.x, ty = threadIdx.y;
    int x = blockIdx.x * 32 + tx;
#pragma unroll
    for (int i = 0; i < 4; i++) {
        int y = blockIdx.y * 32 + ty + i * 8;
        tile[ty + i * 8][tx] = W[y * 1024 + x];
    }
    __syncthreads();
    int x2 = blockIdx.y * 32 + tx;
#pragma unroll
    for (int i = 0; i < 4; i++) {
        int y2 = blockIdx.x * 32 + ty + i * 8;
        Wt[y2 * 1024 + x2] = f2bf(tile[tx][ty + i * 8]);
    }
}

// ------- GEMM: out = A[8192,1024] @ Bt^T + bias  (m97-style 128x128 tile) --
// Bt is [N=1024][K=1024] bf16. 4 waves in 2x2, each computes 64x64.
// B tile staged via global_load_lds (linear layout); A tile reg-staged
// (fp32 convert if AF32) into padded LDS rows (40 shorts) to spread banks.
// mode 0: FP32 store [row][col].  mode 1: bf16 [b,h,l,d].  mode 2: [b,h,d,l].
template<int AF32>
__global__ __launch_bounds__(256) void gemm128(
    const void* __restrict__ Av,
    const unsigned short* __restrict__ Bt,
    const float* __restrict__ bias,
    void* __restrict__ outv, int mode)
{
    constexpr int ALD = 40;  // padded A row length in shorts (80B = 5x16B)
    __shared__ __align__(16) unsigned short ldsA[2][128 * ALD];
    __shared__ __align__(16) unsigned short ldsB[2][128 * 32];

    int tid = threadIdx.x;
    int w = tid >> 6, lane = tid & 63;
    int quad = lane >> 4, l15 = lane & 15;
    int wr = w >> 1, wc = w & 1;
    int m0 = blockIdx.y * 128, n0 = blockIdx.x * 128;

    int arow = tid >> 1, ahs = tid & 1;   // A staging: 2 threads per row

    f4v acc[4][4];
#pragma unroll
    for (int m = 0; m < 4; m++)
#pragma unroll
        for (int n = 0; n < 4; n++) { f4v z = {0.f, 0.f, 0.f, 0.f}; acc[m][n] = z; }

    auto stage = [&](int buf, int k0) {
        // B: 8KB tile = 512 x 16B chunks; wave w covers chunks [w*64,w*64+64)
        // and [256+w*64, ...). chunk c -> (row=c>>2, kchunk=c&3), LDS linear.
        int c = tid;  // == w*64 + lane
        const unsigned short* gb0 = Bt + (size_t)(n0 + (c >> 2)) * 1024 + k0 + (c & 3) * 8;
        GLOAD_LDS(gb0, &ldsB[buf][w * 512]);
        GLOAD_LDS(gb0 + (size_t)64 * 1024, &ldsB[buf][2048 + w * 512]);
        // A: reg-stage 16 elems/thread (row=tid>>1, cols ahs*16..+16)
        s8v v0, v1;
        if (AF32) {
            const float* sa = (const float*)Av + (size_t)(m0 + arow) * 1024 + k0 + ahs * 16;
            v0 = cvt8(sa); v1 = cvt8(sa + 8);
        } else {
            const unsigned short* sa = (const unsigned short*)Av + (size_t)(m0 + arow) * 1024 + k0 + ahs * 16;
            v0 = ld8(sa); v1 = ld8(sa + 8);
        }
        *(s8v*)&ldsA[buf][arow * ALD + ahs * 16] = v0;
        *(s8v*)&ldsA[buf][arow * ALD + ahs * 16 + 8] = v1;
    };

    stage(0, 0);
    for (int t = 0; t < 32; t++) {
        int buf = t & 1;
        if (t < 31) stage(buf ^ 1, (t + 1) * 32);
        __syncthreads();  // drains vmcnt+lgkmcnt: buf fully staged
        s8v af[4], bfr[4];
#pragma unroll
        for (int m = 0; m < 4; m++)
            af[m] = *(const s8v*)&ldsA[buf][(wr * 64 + m * 16 + l15) * ALD + quad * 8];
#pragma unroll
        for (int n = 0; n < 4; n++)
            bfr[n] = *(const s8v*)&ldsB[buf][(wc * 64 + n * 16 + l15) * 32 + quad * 8];
#pragma unroll
        for (int m = 0; m < 4; m++)
#pragma unroll
            for (int n = 0; n < 4; n++)
                acc[m][n] = __builtin_amdgcn_mfma_f32_16x16x32_bf16(af[m], bfr[n], acc[m][n], 0, 0, 0);
        __syncthreads();  // all reads of buf done before restaging it
    }

#pragma unroll
    for (int n = 0; n < 4; n++) {
        int col = n0 + wc * 64 + n * 16 + l15;
        float bvf = bias[col];
#pragma unroll
        for (int m = 0; m < 4; m++) {
#pragma unroll
            for (int r = 0; r < 4; r++) {
                int row = m0 + wr * 64 + m * 16 + quad * 4 + r;
                float v = acc[m][n][r] + bvf;
                if (mode == 0) {
                    ((float*)outv)[(size_t)row * 1024 + col] = v;
                } else {
                    unsigned short* out = (unsigned short*)outv;
                    int bb = row >> 11, l = row & 2047;
                    int hh = col >> 6, d = col & 63;
                    if (mode == 1) out[(((size_t)bb * 16 + hh) * 2048 + l) * 64 + d] = f2bf(v);
                    else           out[(((size_t)bb * 16 + hh) * 64 + d) * 2048 + l] = f2bf(v);
                }
            }
        }
    }
}

// ------- Flash attention (causal) ------------------------------------------
// Q,K: [B,H,L,64] bf16.  Vt: [B,H,64,L] bf16.  O: [B*L,1024] bf16.
// One block = 4 independent waves (16 Q rows each). Two Q-tiles per block
// (qt and 31-qt) -> uniform 33 kt-iterations per block, 1024 blocks.
// No __syncthreads: Pb is wave-private; wave-synchronous DS ordering +
// lgkmcnt fence. Pb rows padded to 72 shorts (144B) to kill bank conflicts.
__global__ __launch_bounds__(256) void attn_kernel(
    const unsigned short* __restrict__ Q,
    const unsigned short* __restrict__ K,
    const unsigned short* __restrict__ Vt,
    unsigned short* __restrict__ O)
{
    __shared__ __align__(16) unsigned short Pb[4][16][72];
    int w = threadIdx.x >> 6, lane = threadIdx.x & 63;
    int quad = lane >> 4, l15 = lane & 15;

    // XCD swizzle: group the 16 blocks sharing (b,h) onto one XCD's L2
    int bid = blockIdx.x;
    int swz = (bid & 7) * 128 + (bid >> 3);
    int xp = swz & 15;
    int h = (swz >> 4) & 15;
    int b = swz >> 8;
    int bh = b * 16 + h;

    const float sscale = 0.125f * LOG2E;  // softmax in log2 domain

#pragma unroll 1
    for (int half = 0; half < 2; half++) {
        int qt = half ? 31 - xp : xp;
        int m0 = qt * 64 + w * 16;

        const unsigned short* qb = Q + ((size_t)bh * 2048 + m0 + l15) * 64 + quad * 8;
        s8v aq0 = ld8(qb), aq1 = ld8(qb + 32);

        float mrun[4], lrun[4];
        f4v oacc[4];
#pragma unroll
        for (int r = 0; r < 4; r++) { mrun[r] = -1e30f; lrun[r] = 0.f; }
#pragma unroll
        for (int t = 0; t < 4; t++) { f4v z = {0.f, 0.f, 0.f, 0.f}; oacc[t] = z; }

#pragma unroll 1
        for (int kt = 0; kt <= qt; kt++) {
            bool diag = (kt == qt);
            f4v sacc[4];
#pragma unroll
            for (int t = 0; t < 4; t++) { f4v z = {0.f, 0.f, 0.f, 0.f}; sacc[t] = z; }
            const unsigned short* kb = K + ((size_t)bh * 2048 + kt * 64 + l15) * 64 + quad * 8;
#pragma unroll
            for (int t = 0; t < 4; t++) {
                s8v b0 = ld8(kb + t * 1024);
                s8v b1 = ld8(kb + t * 1024 + 32);
                sacc[t] = __builtin_amdgcn_mfma_f32_16x16x32_bf16(aq0, b0, sacc[t], 0, 0, 0);
                sacc[t] = __builtin_amdgcn_mfma_f32_16x16x32_bf16(aq1, b1, sacc[t], 0, 0, 0);
            }

#pragma unroll
            for (int r = 0; r < 4; r++) {
                int row = m0 + quad * 4 + r;
                float sv[4];
                float mx = -1e30f;
#pragma unroll
                for (int t = 0; t < 4; t++) {
                    float s = sacc[t][r] * sscale;
                    if (diag) {
                        int key = kt * 64 + t * 16 + l15;
                        if (key > row) s = -1e30f;
                    }
                    sv[t] = s;
                    mx = fmaxf(mx, s);
                }
#pragma unroll
                for (int off = 1; off < 16; off <<= 1)
                    mx = fmaxf(mx, __shfl_xor(mx, off));
                float mnew = fmaxf(mrun[r], mx);
                float alpha = exp2f(mrun[r] - mnew);
                float rs = 0.f;
#pragma unroll
                for (int t = 0; t < 4; t++) {
                    float p = exp2f(sv[t] - mnew);
                    sacc[t][r] = p;
                    rs += p;
                }
#pragma unroll
                for (int off = 1; off < 16; off <<= 1)
                    rs += __shfl_xor(rs, off);
                lrun[r] = lrun[r] * alpha + rs;
                mrun[r] = mnew;
#pragma unroll
                for (int t = 0; t < 4; t++) oacc[t][r] *= alpha;
            }

            // P -> LDS (wave-private slab), wave-synchronous: no barrier
#pragma unroll
            for (int t = 0; t < 4; t++)
#pragma unroll
                for (int r = 0; r < 4; r++)
                    Pb[w][quad * 4 + r][t * 16 + l15] = f2bf(sacc[t][r]);
            asm volatile("s_waitcnt lgkmcnt(0)" ::: "memory");

            const unsigned short* vb = Vt + ((size_t)bh * 64 + l15) * 2048 + kt * 64 + quad * 8;
#pragma unroll
            for (int c = 0; c < 2; c++) {
                s8v apf = *(const s8v*)&Pb[w][l15][c * 32 + quad * 8];
#pragma unroll
                for (int t2 = 0; t2 < 4; t2++) {
                    s8v bvv = ld8(vb + t2 * 16 * 2048 + c * 32);
                    oacc[t2] = __builtin_amdgcn_mfma_f32_16x16x32_bf16(apf, bvv, oacc[t2], 0, 0, 0);
                }
            }
        }

#pragma unroll
        for (int r = 0; r < 4; r++) {
            float inv = 1.f / lrun[r];
            int l = m0 + quad * 4 + r;
#pragma unroll
            for (int t2 = 0; t2 < 4; t2++) {
                O[((size_t)b * 2048 + l) * 1024 + h * 64 + t2 * 16 + l15] = f2bf(oacc[t2][r] * inv);
            }
        }
    }
}

// ------- launch ------------------------------------------------------------
extern "C" void kernel_launch(void* const* d_in, const int* in_sizes, int n_in,
                              void* d_out, int out_size, void* d_ws, size_t ws_size,
                              hipStream_t stream)
{
    const float* queries = (const float*)d_in[0];
    const float* keys    = (const float*)d_in[1];
    const float* values  = (const float*)d_in[2];
    const float* Wq = (const float*)d_in[3];
    const float* bq = (const float*)d_in[4];
    const float* Wk = (const float*)d_in[5];
    const float* bk = (const float*)d_in[6];
    const float* Wv = (const float*)d_in[7];
    const float* bv = (const float*)d_in[8];
    const float* Wo = (const float*)d_in[9];
    const float* bo = (const float*)d_in[10];

    // ws (bf16 elems): 4x1M W^T + 3x8M Q/K/V^T + 8M ow = 72 MB
    unsigned short* ws = (unsigned short*)d_ws;
    const size_t M1 = 1u << 20, M8 = 8u << 20;
    unsigned short* WqT = ws;
    unsigned short* WkT = ws + 1 * M1;
    unsigned short* WvT = ws + 2 * M1;
    unsigned short* WoT = ws + 3 * M1;
    unsigned short* qw  = ws + 4 * M1;      // [B,H,L,64]
    unsigned short* kw  = qw + M8;          // [B,H,L,64]
    unsigned short* vtw = kw + M8;          // [B,H,64,L]
    unsigned short* ow  = vtw + M8;         // [B*L,1024]

    dim3 tb(32, 8), tg(32, 32);
    transpose_w<<<tg, tb, 0, stream>>>(Wq, WqT);
    transpose_w<<<tg, tb, 0, stream>>>(Wk, WkT);
    transpose_w<<<tg, tb, 0, stream>>>(Wv, WvT);
    transpose_w<<<tg, tb, 0, stream>>>(Wo, WoT);

    dim3 gg(8, 64);  // N/128 x M/128 = 512 blocks
    gemm128<1><<<gg, 256, 0, stream>>>(queries, WqT, bq, qw, 1);
    gemm128<1><<<gg, 256, 0, stream>>>(keys,    WkT, bk, kw, 1);
    gemm128<1><<<gg, 256, 0, stream>>>(values,  WvT, bv, vtw, 2);

    attn_kernel<<<dim3(1024), 256, 0, stream>>>(qw, kw, vtw, ow);

    gemm128<0><<<gg, 256, 0, stream>>>(ow, WoT, bo, d_out, 0);  // fp32 out
}

// Round 2
// 571.149 us; speedup vs baseline: 2.2364x; 1.0430x over previous
//
#include <hip/hip_runtime.h>

typedef __attribute__((ext_vector_type(8))) short s8v;
typedef __attribute__((ext_vector_type(4))) short s4v;
typedef __attribute__((ext_vector_type(4))) float f4v;

#define LOG2E 1.44269504088896340736f

__device__ __forceinline__ unsigned short f2bf(float f) {
    unsigned int x = __float_as_uint(f);
    return (unsigned short)((x + 0x7fffu + ((x >> 16) & 1u)) >> 16);
}
__device__ __forceinline__ s8v ld8(const unsigned short* p) {
    return *(const s8v*)p;
}
__device__ __forceinline__ s8v cvt8(const float* p) {
    f4v lo = *(const f4v*)p, hi = *(const f4v*)(p + 4);
    s8v r;
    r[0] = (short)f2bf(lo[0]); r[1] = (short)f2bf(lo[1]);
    r[2] = (short)f2bf(lo[2]); r[3] = (short)f2bf(lo[3]);
    r[4] = (short)f2bf(hi[0]); r[5] = (short)f2bf(hi[1]);
    r[6] = (short)f2bf(hi[2]); r[7] = (short)f2bf(hi[3]);
    return r;
}

// async global->LDS, 16B per lane; LDS dest is wave-uniform base + lane*16
#define GLOAD_LDS(g, l) __builtin_amdgcn_global_load_lds(              \
    (const __attribute__((address_space(1))) void*)(const void*)(g),   \
    (__attribute__((address_space(3))) void*)(void*)(l), 16, 0, 0)

// ------- W transpose + fp32->bf16: Wt[n][k] = bf16(W[k][n]), 1024x1024 -----
__global__ __launch_bounds__(256) void transpose_w(
    const float* __restrict__ W, unsigned short* __restrict__ Wt)
{
    __shared__ float tile[32][33];
    int tx = threadIdx.x, ty = threadIdx.y;
    int x = blockIdx.x * 32 + tx;
#pragma unroll
    for (int i = 0; i < 4; i++) {
        int y = blockIdx.y * 32 + ty + i * 8;
        tile[ty + i * 8][tx] = W[y * 1024 + x];
    }
    __syncthreads();
    int x2 = blockIdx.y * 32 + tx;
#pragma unroll
    for (int i = 0; i < 4; i++) {
        int y2 = blockIdx.x * 32 + ty + i * 8;
        Wt[y2 * 1024 + x2] = f2bf(tile[tx][ty + i * 8]);
    }
}

// ------- activation fp32 -> bf16 (vectorized, grid-stride) -----------------
__global__ __launch_bounds__(256) void cvt_bf16(
    const float* __restrict__ in, unsigned short* __restrict__ out, int n8)
{
    int stride = gridDim.x * 256;
    for (int i = blockIdx.x * 256 + threadIdx.x; i < n8; i += stride)
        *(s8v*)(out + (size_t)i * 8) = cvt8(in + (size_t)i * 8);
}

// ------- GEMM: out = A[8192,1024] @ Bt^T + bias (m97 structure) ------------
// A, Bt both bf16 [*, K=1024]. 128x128 tile, BK=32, both operands staged via
// global_load_lds width-16. 4 waves 2x2, each 64x64 output.
// mode 0: FP32 store [row][col].  mode 1: bf16 [b,h,l,d].  mode 2: [b,h,d,l].
// oscale multiplies (acc+bias) before store (folds softmax scale into Q).
__global__ __launch_bounds__(256) void gemm128(
    const unsigned short* __restrict__ A,
    const unsigned short* __restrict__ Bt,
    const float* __restrict__ bias,
    void* __restrict__ outv, int mode, float oscale)
{
    __shared__ __align__(16) unsigned short ldsA[2][128 * 32];
    __shared__ __align__(16) unsigned short ldsB[2][128 * 32];

    int tid = threadIdx.x;
    int w = tid >> 6, lane = tid & 63;
    int quad = lane >> 4, l15 = lane & 15;
    int wr = w >> 1, wc = w & 1;
    int m0 = blockIdx.y * 128, n0 = blockIdx.x * 128;

    int crow = tid >> 2, ck = (tid & 3) * 8;  // chunk c=tid -> row c>>2, k (c&3)*8

    f4v acc[4][4];
#pragma unroll
    for (int m = 0; m < 4; m++)
#pragma unroll
        for (int n = 0; n < 4; n++) { f4v z = {0.f, 0.f, 0.f, 0.f}; acc[m][n] = z; }

    auto stage = [&](int buf, int k0) {
        const unsigned short* ga = A + (size_t)(m0 + crow) * 1024 + k0 + ck;
        GLOAD_LDS(ga, &ldsA[buf][w * 512]);
        GLOAD_LDS(ga + (size_t)64 * 1024, &ldsA[buf][2048 + w * 512]);
        const unsigned short* gb = Bt + (size_t)(n0 + crow) * 1024 + k0 + ck;
        GLOAD_LDS(gb, &ldsB[buf][w * 512]);
        GLOAD_LDS(gb + (size_t)64 * 1024, &ldsB[buf][2048 + w * 512]);
    };

    stage(0, 0);
    __syncthreads();  // buf0 staged (drains vmcnt)
    for (int t = 0; t < 32; t++) {
        int buf = t & 1;
        if (t < 31) stage(buf ^ 1, (t + 1) * 32);  // prefetch overlaps compute
        s8v af[4], bfr[4];
#pragma unroll
        for (int m = 0; m < 4; m++)
            af[m] = *(const s8v*)&ldsA[buf][(wr * 64 + m * 16 + l15) * 32 + quad * 8];
#pragma unroll
        for (int n = 0; n < 4; n++)
            bfr[n] = *(const s8v*)&ldsB[buf][(wc * 64 + n * 16 + l15) * 32 + quad * 8];
#pragma unroll
        for (int m = 0; m < 4; m++)
#pragma unroll
            for (int n = 0; n < 4; n++)
                acc[m][n] = __builtin_amdgcn_mfma_f32_16x16x32_bf16(af[m], bfr[n], acc[m][n], 0, 0, 0);
        __syncthreads();  // drains vmcnt (next buf ready) + all reads of buf done
    }

#pragma unroll
    for (int n = 0; n < 4; n++) {
        int col = n0 + wc * 64 + n * 16 + l15;
        float bvf = bias[col];
#pragma unroll
        for (int m = 0; m < 4; m++) {
#pragma unroll
            for (int r = 0; r < 4; r++) {
                int row = m0 + wr * 64 + m * 16 + quad * 4 + r;
                float v = (acc[m][n][r] + bvf) * oscale;
                if (mode == 0) {
                    ((float*)outv)[(size_t)row * 1024 + col] = v;
                } else {
                    unsigned short* out = (unsigned short*)outv;
                    int bb = row >> 11, l = row & 2047;
                    int hh = col >> 6, d = col & 63;
                    if (mode == 1) out[(((size_t)bb * 16 + hh) * 2048 + l) * 64 + d] = f2bf(v);
                    else           out[(((size_t)bb * 16 + hh) * 64 + d) * 2048 + l] = f2bf(v);
                }
            }
        }
    }
}

// ------- Flash attention (causal), swapped-QK^T softmax --------------------
// Q,K: [B,H,L,64] bf16 (Q pre-scaled by 0.125*log2e).  Vt: [B,H,64,L] bf16.
// O: [B*L,1024] bf16.  mfma(K,Q) -> S^T: lane = query col, so softmax max is
// 15 in-lane fmax + 2 shuffles; row-sum is per-lane partial, reduced at end.
// Defer-max (THR=8 log2): skip O-rescale when max growth small.
__global__ __launch_bounds__(256) void attn_kernel(
    const unsigned short* __restrict__ Q,
    const unsigned short* __restrict__ K,
    const unsigned short* __restrict__ Vt,
    unsigned short* __restrict__ O)
{
    __shared__ __align__(16) unsigned short Pb[4][16][72];
    int w = threadIdx.x >> 6, lane = threadIdx.x & 63;
    int quad = lane >> 4, l15 = lane & 15;

    // XCD swizzle: group the 16 blocks sharing (b,h) onto one XCD's L2
    int bid = blockIdx.x;
    int swz = (bid & 7) * 128 + (bid >> 3);
    int xp = swz & 15;
    int h = (swz >> 4) & 15;
    int b = swz >> 8;
    int bh = b * 16 + h;

#pragma unroll 1
    for (int half = 0; half < 2; half++) {
        int qt = half ? 31 - xp : xp;
        int m0 = qt * 64 + w * 16;

        const unsigned short* qb = Q + ((size_t)bh * 2048 + m0 + l15) * 64 + quad * 8;
        s8v aq0 = ld8(qb), aq1 = ld8(qb + 32);

        float mrun = -1e30f, lsum = 0.f;
        f4v oacc[4];
#pragma unroll
        for (int t = 0; t < 4; t++) { f4v z = {0.f, 0.f, 0.f, 0.f}; oacc[t] = z; }

#pragma unroll 1
        for (int kt = 0; kt <= qt; kt++) {
            f4v sacc[4];
#pragma unroll
            for (int t = 0; t < 4; t++) { f4v z = {0.f, 0.f, 0.f, 0.f}; sacc[t] = z; }
            const unsigned short* kb = K + ((size_t)bh * 2048 + kt * 64 + l15) * 64 + quad * 8;
#pragma unroll
            for (int t = 0; t < 4; t++) {
                s8v k0 = ld8(kb + t * 1024);
                s8v k1 = ld8(kb + t * 1024 + 32);
                sacc[t] = __builtin_amdgcn_mfma_f32_16x16x32_bf16(k0, aq0, sacc[t], 0, 0, 0);
                sacc[t] = __builtin_amdgcn_mfma_f32_16x16x32_bf16(k1, aq1, sacc[t], 0, 0, 0);
            }
            // sacc[t][r] = S[key = kt*64+t*16+quad*4+r][query = m0+l15] (log2 units)

            if (kt == qt) {
                int qrow = m0 + l15;
#pragma unroll
                for (int t = 0; t < 4; t++)
#pragma unroll
                    for (int r = 0; r < 4; r++) {
                        int key = kt * 64 + t * 16 + quad * 4 + r;
                        if (key > qrow) sacc[t][r] = -1e30f;
                    }
            }

            float mx = sacc[0][0];
#pragma unroll
            for (int t = 0; t < 4; t++)
#pragma unroll
                for (int r = 0; r < 4; r++)
                    mx = fmaxf(mx, sacc[t][r]);
            mx = fmaxf(mx, __shfl_xor(mx, 16));
            mx = fmaxf(mx, __shfl_xor(mx, 32));  // replicated across quads

            if (__any(mx > mrun + 8.0f)) {       // wave-uniform branch
                float mnew = fmaxf(mrun, mx);
                float alpha = exp2f(mrun - mnew);
                lsum *= alpha;
#pragma unroll
                for (int r = 0; r < 4; r++) {
                    float ar = __shfl(alpha, quad * 4 + r);  // alpha of oacc row
#pragma unroll
                    for (int t2 = 0; t2 < 4; t2++) oacc[t2][r] *= ar;
                }
                mrun = mnew;
            }

            float rs = 0.f;
#pragma unroll
            for (int t = 0; t < 4; t++) {
                s4v p4;
#pragma unroll
                for (int r = 0; r < 4; r++) {
                    float p = exp2f(sacc[t][r] - mrun);
                    rs += p;
                    p4[r] = (short)f2bf(p);
                }
                *(s4v*)&Pb[w][l15][t * 16 + quad * 4] = p4;  // ds_write_b64
            }
            lsum += rs;
            asm volatile("s_waitcnt lgkmcnt(0)" ::: "memory");

            const unsigned short* vb = Vt + ((size_t)bh * 64 + l15) * 2048 + kt * 64 + quad * 8;
#pragma unroll
            for (int c = 0; c < 2; c++) {
                s8v apf = *(const s8v*)&Pb[w][l15][c * 32 + quad * 8];
#pragma unroll
                for (int t2 = 0; t2 < 4; t2++) {
                    s8v bvv = ld8(vb + t2 * 16 * 2048 + c * 32);
                    oacc[t2] = __builtin_amdgcn_mfma_f32_16x16x32_bf16(apf, bvv, oacc[t2], 0, 0, 0);
                }
            }
        }

        float ltot = lsum;
        ltot += __shfl_xor(ltot, 16);
        ltot += __shfl_xor(ltot, 32);
        float inv = 1.f / ltot;
#pragma unroll
        for (int r = 0; r < 4; r++) {
            float ir = __shfl(inv, quad * 4 + r);
            int l = m0 + quad * 4 + r;
#pragma unroll
            for (int t2 = 0; t2 < 4; t2++) {
                O[((size_t)b * 2048 + l) * 1024 + h * 64 + t2 * 16 + l15] = f2bf(oacc[t2][r] * ir);
            }
        }
    }
}

// ------- launch ------------------------------------------------------------
extern "C" void kernel_launch(void* const* d_in, const int* in_sizes, int n_in,
                              void* d_out, int out_size, void* d_ws, size_t ws_size,
                              hipStream_t stream)
{
    const float* queries = (const float*)d_in[0];
    const float* keys    = (const float*)d_in[1];
    const float* values  = (const float*)d_in[2];
    const float* Wq = (const float*)d_in[3];
    const float* bq = (const float*)d_in[4];
    const float* Wk = (const float*)d_in[5];
    const float* bk = (const float*)d_in[6];
    const float* Wv = (const float*)d_in[7];
    const float* bv = (const float*)d_in[8];
    const float* Wo = (const float*)d_in[9];
    const float* bo = (const float*)d_in[10];

    // ws (bf16 elems): 4x1M W^T + 3x8M Q/K/V^T + 8M ow = 72 MB
    unsigned short* ws = (unsigned short*)d_ws;
    const size_t M1 = 1u << 20, M8 = 8u << 20;
    unsigned short* WqT = ws;
    unsigned short* WkT = ws + 1 * M1;
    unsigned short* WvT = ws + 2 * M1;
    unsigned short* WoT = ws + 3 * M1;
    unsigned short* qw  = ws + 4 * M1;      // [B,H,L,64]
    unsigned short* kw  = qw + M8;          // [B,H,L,64]
    unsigned short* vtw = kw + M8;          // [B,H,64,L]
    unsigned short* ow  = vtw + M8;         // [B*L,1024]; also cvt scratch pre-attn

    const float sscale = 0.125f * LOG2E;

    dim3 tb(32, 8), tg(32, 32);
    transpose_w<<<tg, tb, 0, stream>>>(Wq, WqT);
    transpose_w<<<tg, tb, 0, stream>>>(Wk, WkT);
    transpose_w<<<tg, tb, 0, stream>>>(Wv, WvT);
    transpose_w<<<tg, tb, 0, stream>>>(Wo, WoT);

    dim3 gg(8, 64);  // N/128 x M/128
    const int n8 = (int)(M8 / 8);
    // ow slab doubles as the bf16-activation scratch (stream-serialized reuse)
    cvt_bf16<<<2048, 256, 0, stream>>>(queries, ow, n8);
    gemm128<<<gg, 256, 0, stream>>>(ow, WqT, bq, qw, 1, sscale);
    cvt_bf16<<<2048, 256, 0, stream>>>(keys, ow, n8);
    gemm128<<<gg, 256, 0, stream>>>(ow, WkT, bk, kw, 1, 1.0f);
    cvt_bf16<<<2048, 256, 0, stream>>>(values, ow, n8);
    gemm128<<<gg, 256, 0, stream>>>(ow, WvT, bv, vtw, 2, 1.0f);

    attn_kernel<<<dim3(1024), 256, 0, stream>>>(qw, kw, vtw, ow);

    gemm128<<<gg, 256, 0, stream>>>(ow, WoT, bo, d_out, 0, 1.0f);  // fp32 out
}

// Round 4
// 413.021 us; speedup vs baseline: 3.0926x; 1.3829x over previous
//
#include <hip/hip_runtime.h>

typedef __attribute__((ext_vector_type(8))) short s8v;
typedef __attribute__((ext_vector_type(4))) short s4v;
typedef __attribute__((ext_vector_type(4))) float f4v;
typedef __attribute__((ext_vector_type(4))) unsigned int u4v;

#define LOG2E 1.44269504088896340736f

__device__ __forceinline__ unsigned short f2bf(float f) {
    unsigned int x = __float_as_uint(f);
    return (unsigned short)((x + 0x7fffu + ((x >> 16) & 1u)) >> 16);
}
__device__ __forceinline__ s8v ld8(const unsigned short* p) {
    return *(const s8v*)p;
}
__device__ __forceinline__ s8v cvt8(const float* p) {
    f4v lo = *(const f4v*)p, hi = *(const f4v*)(p + 4);
    s8v r;
    r[0] = (short)f2bf(lo[0]); r[1] = (short)f2bf(lo[1]);
    r[2] = (short)f2bf(lo[2]); r[3] = (short)f2bf(lo[3]);
    r[4] = (short)f2bf(hi[0]); r[5] = (short)f2bf(hi[1]);
    r[6] = (short)f2bf(hi[2]); r[7] = (short)f2bf(hi[3]);
    return r;
}

// async global->LDS, 16B per lane; LDS dest is wave-uniform base + lane*16
#define GLOAD_LDS(g, l) __builtin_amdgcn_global_load_lds(              \
    (const __attribute__((address_space(1))) void*)(const void*)(g),   \
    (__attribute__((address_space(3))) void*)(void*)(l), 16, 0, 0)

// ------- W transpose + fp32->bf16: Wt[n][k] = bf16(W[k][n]), 1024x1024 -----
__global__ __launch_bounds__(256) void transpose_w(
    const float* __restrict__ W, unsigned short* __restrict__ Wt)
{
    __shared__ float tile[32][33];
    int tx = threadIdx.x, ty = threadIdx.y;
    int x = blockIdx.x * 32 + tx;
#pragma unroll
    for (int i = 0; i < 4; i++) {
        int y = blockIdx.y * 32 + ty + i * 8;
        tile[ty + i * 8][tx] = W[y * 1024 + x];
    }
    __syncthreads();
    int x2 = blockIdx.y * 32 + tx;
#pragma unroll
    for (int i = 0; i < 4; i++) {
        int y2 = blockIdx.x * 32 + ty + i * 8;
        Wt[y2 * 1024 + x2] = f2bf(tile[tx][ty + i * 8]);
    }
}

// ------- activation fp32 -> bf16 (vectorized, grid-stride) -----------------
__global__ __launch_bounds__(256) void cvt_bf16(
    const float* __restrict__ in, unsigned short* __restrict__ out, int n8)
{
    int stride = gridDim.x * 256;
    for (int i = blockIdx.x * 256 + threadIdx.x; i < n8; i += stride)
        *(s8v*)(out + (size_t)i * 8) = cvt8(in + (size_t)i * 8);
}

// ------- GEMM: out = A[8192,1024] @ Bt^T + bias (m97 structure) ------------
// A, Bt both bf16 [*, K=1024]. 128x128 tile, BK=32, both operands staged via
// global_load_lds width-16. 4 waves 2x2, each 64x64 output.
// mode 0: FP32 [row][col].  mode 1: bf16 [b,h,l,d].
// mode 2: bf16 [b,h,d,l'] with l' = key-permuted low-6-bits (PV fragment
//         layout: s(j) = Q<<4 | c<<3 | t<<1 | b from j = t<<4|Q<<2|c<<1|b).
__global__ __launch_bounds__(256) void gemm128(
    const unsigned short* __restrict__ A,
    const unsigned short* __restrict__ Bt,
    const float* __restrict__ bias,
    void* __restrict__ outv, int mode, float oscale)
{
    __shared__ __align__(16) unsigned short ldsA[2][128 * 32];
    __shared__ __align__(16) unsigned short ldsB[2][128 * 32];

    int tid = threadIdx.x;
    int w = tid >> 6, lane = tid & 63;
    int quad = lane >> 4, l15 = lane & 15;
    int wr = w >> 1, wc = w & 1;
    int m0 = blockIdx.y * 128, n0 = blockIdx.x * 128;

    int crow = tid >> 2, ck = (tid & 3) * 8;  // chunk c=tid -> row c>>2, k (c&3)*8

    f4v acc[4][4];
#pragma unroll
    for (int m = 0; m < 4; m++)
#pragma unroll
        for (int n = 0; n < 4; n++) { f4v z = {0.f, 0.f, 0.f, 0.f}; acc[m][n] = z; }

    auto stage = [&](int buf, int k0) {
        const unsigned short* ga = A + (size_t)(m0 + crow) * 1024 + k0 + ck;
        GLOAD_LDS(ga, &ldsA[buf][w * 512]);
        GLOAD_LDS(ga + (size_t)64 * 1024, &ldsA[buf][2048 + w * 512]);
        const unsigned short* gb = Bt + (size_t)(n0 + crow) * 1024 + k0 + ck;
        GLOAD_LDS(gb, &ldsB[buf][w * 512]);
        GLOAD_LDS(gb + (size_t)64 * 1024, &ldsB[buf][2048 + w * 512]);
    };

    stage(0, 0);
    __syncthreads();  // buf0 staged (drains vmcnt)
    for (int t = 0; t < 32; t++) {
        int buf = t & 1;
        if (t < 31) stage(buf ^ 1, (t + 1) * 32);  // prefetch overlaps compute
        s8v af[4], bfr[4];
#pragma unroll
        for (int m = 0; m < 4; m++)
            af[m] = *(const s8v*)&ldsA[buf][(wr * 64 + m * 16 + l15) * 32 + quad * 8];
#pragma unroll
        for (int n = 0; n < 4; n++)
            bfr[n] = *(const s8v*)&ldsB[buf][(wc * 64 + n * 16 + l15) * 32 + quad * 8];
#pragma unroll
        for (int m = 0; m < 4; m++)
#pragma unroll
            for (int n = 0; n < 4; n++)
                acc[m][n] = __builtin_amdgcn_mfma_f32_16x16x32_bf16(af[m], bfr[n], acc[m][n], 0, 0, 0);
        __syncthreads();  // reads of buf done + next stage drained (vmcnt0)
    }

#pragma unroll
    for (int n = 0; n < 4; n++) {
        int col = n0 + wc * 64 + n * 16 + l15;
        float bvf = bias[col];
#pragma unroll
        for (int m = 0; m < 4; m++) {
#pragma unroll
            for (int r = 0; r < 4; r++) {
                int row = m0 + wr * 64 + m * 16 + quad * 4 + r;
                float v = (acc[m][n][r] + bvf) * oscale;
                if (mode == 0) {
                    ((float*)outv)[(size_t)row * 1024 + col] = v;
                } else {
                    unsigned short* out = (unsigned short*)outv;
                    int bb = row >> 11, l = row & 2047;
                    int hh = col >> 6, d = col & 63;
                    if (mode == 1) {
                        out[(((size_t)bb * 16 + hh) * 2048 + l) * 64 + d] = f2bf(v);
                    } else {
                        int j = l & 63;  // key -> storage slot permutation
                        int s = ((j & 0x0C) << 2) | ((j & 0x02) << 2) |
                                ((j & 0x30) >> 3) | (j & 1);
                        int lp = (l & ~63) | s;
                        out[(((size_t)bb * 16 + hh) * 64 + d) * 2048 + lp] = f2bf(v);
                    }
                }
            }
        }
    }
}

// ------- Flash attention (causal), swapped-QK^T, LDS-shared K/V ------------
// Q,K: [B,H,L,64] bf16 (Q pre-scaled by 0.125*log2e).
// Vt: [B,H,64,L] bf16, key-permuted within 64-groups (see gemm mode 2).
// O: [B*L,1024] bf16.
// K/V tiles staged into LDS once per block (shared by 4 waves), double-
// buffered, global_load_lds w16, XOR-swizzled source (byte ^= (row&7)<<4)
// for conflict-free ds_read_b128.  P never touches LDS: lane-local cvt_pk
// fragments feed PV directly (custom k-slot->key mapping matches Vt perm).
__global__ __launch_bounds__(256) void attn_kernel(
    const unsigned short* __restrict__ Q,
    const unsigned short* __restrict__ K,
    const unsigned short* __restrict__ Vt,
    unsigned short* __restrict__ O)
{
    __shared__ __align__(16) unsigned short Kb[2][64 * 64];
    __shared__ __align__(16) unsigned short Vb[2][64 * 64];

    int tid = threadIdx.x;
    int w = tid >> 6, lane = tid & 63;
    int quad = lane >> 4, l15 = lane & 15;

    // XCD swizzle: the 16 blocks sharing (b,h) map to one XCD's L2
    int bid = blockIdx.x;
    int swz = (bid & 7) * 128 + (bid >> 3);
    int xp = swz & 15;
    int h = (swz >> 4) & 15;
    int b = swz >> 8;
    int bh = b * 16 + h;

    // staging: chunk c = tid (+256): row c>>3 (0..31 / 32..63), 16B chunk c&7
    int srow = tid >> 3;
    int soff = ((tid & 7) * 16) ^ ((srow & 7) << 4);  // pre-swizzled src offset
    const unsigned short* Kbase = K + (size_t)bh * 2048 * 64;
    const unsigned short* Vbase = Vt + (size_t)bh * 64 * 2048;

    auto stageK = [&](int buf, int kt) {
        const unsigned short* g1 = Kbase + (size_t)(kt * 64 + srow) * 64 + (soff >> 1);
        GLOAD_LDS(g1, &Kb[buf][w * 512]);
        GLOAD_LDS(g1 + (size_t)32 * 64, &Kb[buf][2048 + w * 512]);
    };
    auto stageV = [&](int buf, int kt) {
        const unsigned short* g1 = Vbase + (size_t)srow * 2048 + kt * 64 + (soff >> 1);
        GLOAD_LDS(g1, &Vb[buf][w * 512]);
        GLOAD_LDS(g1 + (size_t)32 * 2048, &Vb[buf][2048 + w * 512]);
    };

    int rswz = (l15 & 7) << 4;  // read-side XOR (row&7 == l15&7 for our rows)

#pragma unroll 1
    for (int half = 0; half < 2; half++) {
        int qt = half ? 31 - xp : xp;
        int m0 = qt * 64 + w * 16;

        const unsigned short* qb = Q + ((size_t)bh * 2048 + m0 + l15) * 64 + quad * 8;
        s8v aq0 = ld8(qb), aq1 = ld8(qb + 32);

        float mrun = -1e30f, lsum = 0.f;
        f4v oacc[4];
#pragma unroll
        for (int t = 0; t < 4; t++) { f4v z = {0.f, 0.f, 0.f, 0.f}; oacc[t] = z; }

        stageK(0, 0);
        stageV(0, 0);
        __syncthreads();

#pragma unroll 1
        for (int kt = 0; kt <= qt; kt++) {
            int buf = kt & 1;
            if (kt < qt) { stageK(buf ^ 1, kt + 1); stageV(buf ^ 1, kt + 1); }

            f4v sacc[4];
#pragma unroll
            for (int t = 0; t < 4; t++) { f4v z = {0.f, 0.f, 0.f, 0.f}; sacc[t] = z; }
            const char* kbp = (const char*)&Kb[buf][0];
#pragma unroll
            for (int t = 0; t < 4; t++) {
                int rb = (t * 16 + l15) * 128;
                s8v k0 = *(const s8v*)(kbp + rb + ((quad * 16) ^ rswz));
                s8v k1 = *(const s8v*)(kbp + rb + ((64 + quad * 16) ^ rswz));
                sacc[t] = __builtin_amdgcn_mfma_f32_16x16x32_bf16(k0, aq0, sacc[t], 0, 0, 0);
                sacc[t] = __builtin_amdgcn_mfma_f32_16x16x32_bf16(k1, aq1, sacc[t], 0, 0, 0);
            }
            // sacc[t][r] = S[key_local = t*16+quad*4+r][query = m0+l15] (log2)

            if (kt == qt) {
                int qrow = w * 16 + l15;  // query index within the 64-wide qt tile
#pragma unroll
                for (int t = 0; t < 4; t++)
#pragma unroll
                    for (int r = 0; r < 4; r++) {
                        int key = t * 16 + quad * 4 + r;
                        if (key > qrow) sacc[t][r] = -1e30f;
                    }
            }

            float mx = sacc[0][0];
#pragma unroll
            for (int t = 0; t < 4; t++)
#pragma unroll
                for (int r = 0; r < 4; r++)
                    mx = fmaxf(mx, sacc[t][r]);
            mx = fmaxf(mx, __shfl_xor(mx, 16));
            mx = fmaxf(mx, __shfl_xor(mx, 32));  // per-query max, all quads

            if (__any(mx > mrun + 8.0f)) {       // defer-max, wave-uniform
                float mnew = fmaxf(mrun, mx);
                float alpha = exp2f(mrun - mnew);
                lsum *= alpha;
#pragma unroll
                for (int r = 0; r < 4; r++) {
                    float ar = __shfl(alpha, quad * 4 + r);
#pragma unroll
                    for (int t2 = 0; t2 < 4; t2++) oacc[t2][r] *= ar;
                }
                mrun = mnew;
            }

            float rs = 0.f;
#pragma unroll
            for (int t = 0; t < 4; t++)
#pragma unroll
                for (int r = 0; r < 4; r++) {
                    float p = exp2f(sacc[t][r] - mrun);
                    rs += p;
                    sacc[t][r] = p;
                }
            lsum += rs;

            // P -> bf16 pairs, lane-local (k-slot->key mapping matches Vt perm)
            unsigned int pwv[4][2];
#pragma unroll
            for (int t = 0; t < 4; t++) {
                asm("v_cvt_pk_bf16_f32 %0, %1, %2"
                    : "=v"(pwv[t][0]) : "v"(sacc[t][0]), "v"(sacc[t][1]));
                asm("v_cvt_pk_bf16_f32 %0, %1, %2"
                    : "=v"(pwv[t][1]) : "v"(sacc[t][2]), "v"(sacc[t][3]));
            }

            const char* vbp = (const char*)&Vb[buf][0];
#pragma unroll
            for (int c = 0; c < 2; c++) {
                u4v aw;
                aw[0] = pwv[0][c]; aw[1] = pwv[1][c];
                aw[2] = pwv[2][c]; aw[3] = pwv[3][c];
                s8v apf = __builtin_bit_cast(s8v, aw);
#pragma unroll
                for (int t2 = 0; t2 < 4; t2++) {
                    int rb = (t2 * 16 + l15) * 128;
                    s8v bvv = *(const s8v*)(vbp + rb + ((quad * 32 + c * 16) ^ rswz));
                    oacc[t2] = __builtin_amdgcn_mfma_f32_16x16x32_bf16(apf, bvv, oacc[t2], 0, 0, 0);
                }
            }
            __syncthreads();  // reads of buf done; next stage drained
        }

        float ltot = lsum;
        ltot += __shfl_xor(ltot, 16);
        ltot += __shfl_xor(ltot, 32);
        float inv = 1.f / ltot;
#pragma unroll
        for (int r = 0; r < 4; r++) {
            float ir = __shfl(inv, quad * 4 + r);
            int l = m0 + quad * 4 + r;
#pragma unroll
            for (int t2 = 0; t2 < 4; t2++) {
                O[((size_t)b * 2048 + l) * 1024 + h * 64 + t2 * 16 + l15] = f2bf(oacc[t2][r] * ir);
            }
        }
    }
}

// ------- launch ------------------------------------------------------------
extern "C" void kernel_launch(void* const* d_in, const int* in_sizes, int n_in,
                              void* d_out, int out_size, void* d_ws, size_t ws_size,
                              hipStream_t stream)
{
    const float* queries = (const float*)d_in[0];
    const float* keys    = (const float*)d_in[1];
    const float* values  = (const float*)d_in[2];
    const float* Wq = (const float*)d_in[3];
    const float* bq = (const float*)d_in[4];
    const float* Wk = (const float*)d_in[5];
    const float* bk = (const float*)d_in[6];
    const float* Wv = (const float*)d_in[7];
    const float* bv = (const float*)d_in[8];
    const float* Wo = (const float*)d_in[9];
    const float* bo = (const float*)d_in[10];

    // ws (bf16 elems): 4x1M W^T + 3x8M Q/K/V^T + 8M ow = 72 MB
    unsigned short* ws = (unsigned short*)d_ws;
    const size_t M1 = 1u << 20, M8 = 8u << 20;
    unsigned short* WqT = ws;
    unsigned short* WkT = ws + 1 * M1;
    unsigned short* WvT = ws + 2 * M1;
    unsigned short* WoT = ws + 3 * M1;
    unsigned short* qw  = ws + 4 * M1;      // [B,H,L,64]
    unsigned short* kw  = qw + M8;          // [B,H,L,64]
    unsigned short* vtw = kw + M8;          // [B,H,64,L] (key-permuted)
    unsigned short* ow  = vtw + M8;         // [B*L,1024]; also cvt scratch

    const float sscale = 0.125f * LOG2E;

    dim3 tb(32, 8), tg(32, 32);
    transpose_w<<<tg, tb, 0, stream>>>(Wq, WqT);
    transpose_w<<<tg, tb, 0, stream>>>(Wk, WkT);
    transpose_w<<<tg, tb, 0, stream>>>(Wv, WvT);
    transpose_w<<<tg, tb, 0, stream>>>(Wo, WoT);

    dim3 gg(8, 64);  // N/128 x M/128
    const int n8 = (int)(M8 / 8);
    cvt_bf16<<<2048, 256, 0, stream>>>(queries, ow, n8);
    gemm128<<<gg, 256, 0, stream>>>(ow, WqT, bq, qw, 1, sscale);
    cvt_bf16<<<2048, 256, 0, stream>>>(keys, ow, n8);
    gemm128<<<gg, 256, 0, stream>>>(ow, WkT, bk, kw, 1, 1.0f);
    cvt_bf16<<<2048, 256, 0, stream>>>(values, ow, n8);
    gemm128<<<gg, 256, 0, stream>>>(ow, WvT, bv, vtw, 2, 1.0f);

    attn_kernel<<<dim3(1024), 256, 0, stream>>>(qw, kw, vtw, ow);

    gemm128<<<gg, 256, 0, stream>>>(ow, WoT, bo, d_out, 0, 1.0f);  // fp32 out
}

// Round 5
// 391.700 us; speedup vs baseline: 3.2609x; 1.0544x over previous
//
#include <hip/hip_runtime.h>

typedef __attribute__((ext_vector_type(8))) short s8v;
typedef __attribute__((ext_vector_type(4))) short s4v;
typedef __attribute__((ext_vector_type(4))) float f4v;
typedef __attribute__((ext_vector_type(4))) unsigned int u4v;

#define LOG2E 1.44269504088896340736f

__device__ __forceinline__ unsigned short f2bf(float f) {
    unsigned int x = __float_as_uint(f);
    return (unsigned short)((x + 0x7fffu + ((x >> 16) & 1u)) >> 16);
}
__device__ __forceinline__ s8v ld8(const unsigned short* p) {
    return *(const s8v*)p;
}

// async global->LDS, 16B per lane; LDS dest is wave-uniform base + lane*16
#define GLOAD_LDS(g, l) __builtin_amdgcn_global_load_lds(              \
    (const __attribute__((address_space(1))) void*)(const void*)(g),   \
    (__attribute__((address_space(3))) void*)(void*)(l), 16, 0, 0)

// ------- 4x W transpose + fp32->bf16 in one launch -------------------------
__global__ __launch_bounds__(256) void transpose_w4(
    const float* __restrict__ W0, const float* __restrict__ W1,
    const float* __restrict__ W2, const float* __restrict__ W3,
    unsigned short* __restrict__ T0, unsigned short* __restrict__ T1,
    unsigned short* __restrict__ T2, unsigned short* __restrict__ T3)
{
    __shared__ float tile[32][33];
    int z = blockIdx.z;
    const float* W = z == 0 ? W0 : z == 1 ? W1 : z == 2 ? W2 : W3;
    unsigned short* Wt = z == 0 ? T0 : z == 1 ? T1 : z == 2 ? T2 : T3;
    int tx = threadIdx.x, ty = threadIdx.y;
    int x = blockIdx.x * 32 + tx;
#pragma unroll
    for (int i = 0; i < 4; i++) {
        int y = blockIdx.y * 32 + ty + i * 8;
        tile[ty + i * 8][tx] = W[y * 1024 + x];
    }
    __syncthreads();
    int x2 = blockIdx.y * 32 + tx;
#pragma unroll
    for (int i = 0; i < 4; i++) {
        int y2 = blockIdx.x * 32 + ty + i * 8;
        Wt[y2 * 1024 + x2] = f2bf(tile[tx][ty + i * 8]);
    }
}

// ------- fused QKV GEMM: {q,k,v}[8192,1024]fp32 @ W^T + bias ---------------
// One launch, 1536 blocks (3 gemms x 8 col x 64 row).  XCD-swizzled so the
// 8 column-blocks sharing an A row-panel land on one XCD (A read 1x from L3).
// A fp32 reg-staged with in-register cvt_pk (late-write T14 schedule);
// B bf16 via global_load_lds w16.  128x128 tile, BK=32, 1 barrier/iter.
// z=0: out qw [b,h,l,d] scaled by sscale. z=1: kw [b,h,l,d]. z=2: vtw
// [b,h,d,l'] with l' = key-permuted low-6 bits (PV fragment layout).
__global__ __launch_bounds__(256) void qkv_gemm(
    const float* __restrict__ Aq, const float* __restrict__ Ak,
    const float* __restrict__ Avv,
    const unsigned short* __restrict__ BtQ, const unsigned short* __restrict__ BtK,
    const unsigned short* __restrict__ BtV,
    const float* __restrict__ bq, const float* __restrict__ bk,
    const float* __restrict__ bv,
    unsigned short* __restrict__ qo, unsigned short* __restrict__ ko,
    unsigned short* __restrict__ vo, float sscale)
{
    __shared__ __align__(16) unsigned short ldsA[2][128 * 32];
    __shared__ __align__(16) unsigned short ldsB[2][128 * 32];

    // decode: xcd c = i&7 gets 24 consecutive (z,row) panels, all 8 cols each
    int i = blockIdx.x;
    int c = i & 7, j = i >> 3;
    int bx = j & 7, zy = c * 24 + (j >> 3);
    int z = zy >> 6, by = zy & 63;

    const float* A = z == 0 ? Aq : z == 1 ? Ak : Avv;
    const unsigned short* Bt = z == 0 ? BtQ : z == 1 ? BtK : BtV;
    const float* bias = z == 0 ? bq : z == 1 ? bk : bv;
    unsigned short* out = z == 0 ? qo : z == 1 ? ko : vo;
    float oscale = z == 0 ? sscale : 1.0f;

    int tid = threadIdx.x;
    int w = tid >> 6, lane = tid & 63;
    int quad = lane >> 4, l15 = lane & 15;
    int wr = w >> 1, wc = w & 1;
    int m0 = by * 128, n0 = bx * 128;

    int arow = tid >> 1, ahs = tid & 1;        // A: 2 threads/row, 16 floats each
    int crow = tid >> 2, ck = (tid & 3) * 8;   // B: 4 threads/row, 16B chunks

    const float* ap = A + (size_t)(m0 + arow) * 1024 + ahs * 16;
    const unsigned short* bp = Bt + (size_t)(n0 + crow) * 1024 + ck;
    unsigned short* aw0 = &ldsA[0][arow * 32 + ahs * 16];
    unsigned short* aw1 = &ldsA[1][arow * 32 + ahs * 16];

    f4v acc[4][4];
#pragma unroll
    for (int m = 0; m < 4; m++)
#pragma unroll
        for (int n = 0; n < 4; n++) { f4v zz = {0.f, 0.f, 0.f, 0.f}; acc[m][n] = zz; }

    auto stageB = [&](int buf, int k0) {
        GLOAD_LDS(bp + k0, &ldsB[buf][w * 512]);
        GLOAD_LDS(bp + k0 + (size_t)64 * 1024, &ldsB[buf][2048 + w * 512]);
    };
    auto cvtwrA = [&](unsigned short* dst, f4v a0, f4v a1, f4v a2, f4v a3) {
        unsigned int w0, w1, w2, w3, w4, w5, w6, w7;
        asm("v_cvt_pk_bf16_f32 %0, %1, %2" : "=v"(w0) : "v"(a0[0]), "v"(a0[1]));
        asm("v_cvt_pk_bf16_f32 %0, %1, %2" : "=v"(w1) : "v"(a0[2]), "v"(a0[3]));
        asm("v_cvt_pk_bf16_f32 %0, %1, %2" : "=v"(w2) : "v"(a1[0]), "v"(a1[1]));
        asm("v_cvt_pk_bf16_f32 %0, %1, %2" : "=v"(w3) : "v"(a1[2]), "v"(a1[3]));
        asm("v_cvt_pk_bf16_f32 %0, %1, %2" : "=v"(w4) : "v"(a2[0]), "v"(a2[1]));
        asm("v_cvt_pk_bf16_f32 %0, %1, %2" : "=v"(w5) : "v"(a2[2]), "v"(a2[3]));
        asm("v_cvt_pk_bf16_f32 %0, %1, %2" : "=v"(w6) : "v"(a3[0]), "v"(a3[1]));
        asm("v_cvt_pk_bf16_f32 %0, %1, %2" : "=v"(w7) : "v"(a3[2]), "v"(a3[3]));
        u4v lo; lo[0] = w0; lo[1] = w1; lo[2] = w2; lo[3] = w3;
        u4v hi; hi[0] = w4; hi[1] = w5; hi[2] = w6; hi[3] = w7;
        *(u4v*)dst = lo;
        *(u4v*)(dst + 8) = hi;
    };

    // prologue: stage tile 0 into buf 0
    {
        f4v a0 = *(const f4v*)(ap), a1 = *(const f4v*)(ap + 4);
        f4v a2 = *(const f4v*)(ap + 8), a3 = *(const f4v*)(ap + 12);
        stageB(0, 0);
        cvtwrA(aw0, a0, a1, a2, a3);
    }
    __syncthreads();

    for (int t = 0; t < 32; t++) {
        int buf = t & 1;
        bool pf = t < 31;
        f4v a0, a1, a2, a3;
        if (pf) {
            const float* an = ap + (t + 1) * 32;
            a0 = *(const f4v*)(an); a1 = *(const f4v*)(an + 4);
            a2 = *(const f4v*)(an + 8); a3 = *(const f4v*)(an + 12);
            stageB(buf ^ 1, (t + 1) * 32);
        }
        s8v af[4], bfr[4];
#pragma unroll
        for (int m = 0; m < 4; m++)
            af[m] = *(const s8v*)&ldsA[buf][(wr * 64 + m * 16 + l15) * 32 + quad * 8];
#pragma unroll
        for (int n = 0; n < 4; n++)
            bfr[n] = *(const s8v*)&ldsB[buf][(wc * 64 + n * 16 + l15) * 32 + quad * 8];
#pragma unroll
        for (int m = 0; m < 4; m++)
#pragma unroll
            for (int n = 0; n < 4; n++)
                acc[m][n] = __builtin_amdgcn_mfma_f32_16x16x32_bf16(af[m], bfr[n], acc[m][n], 0, 0, 0);
        if (pf) cvtwrA(buf ? aw0 : aw1, a0, a1, a2, a3);
        __syncthreads();  // drains vmcnt (B staged) + lgkm (A written) + reads done
    }

#pragma unroll
    for (int n = 0; n < 4; n++) {
        int col = n0 + wc * 64 + n * 16 + l15;
        float bvf = bias[col];
#pragma unroll
        for (int m = 0; m < 4; m++) {
#pragma unroll
            for (int r = 0; r < 4; r++) {
                int row = m0 + wr * 64 + m * 16 + quad * 4 + r;
                float v = (acc[m][n][r] + bvf) * oscale;
                int bb = row >> 11, l = row & 2047;
                int hh = col >> 6, d = col & 63;
                if (z != 2) {
                    out[(((size_t)bb * 16 + hh) * 2048 + l) * 64 + d] = f2bf(v);
                } else {
                    int jj = l & 63;  // key -> storage slot permutation
                    int s = ((jj & 0x0C) << 2) | ((jj & 0x02) << 2) |
                            ((jj & 0x30) >> 3) | (jj & 1);
                    int lp = (l & ~63) | s;
                    out[(((size_t)bb * 16 + hh) * 64 + d) * 2048 + lp] = f2bf(v);
                }
            }
        }
    }
}

// ------- O-projection GEMM: out_fp32 = ow[8192,1024]bf16 @ WoT^T + bo ------
// m97 structure, both operands via global_load_lds, XCD-swizzled 1D grid.
__global__ __launch_bounds__(256) void ogemm(
    const unsigned short* __restrict__ A,
    const unsigned short* __restrict__ Bt,
    const float* __restrict__ bias,
    float* __restrict__ out)
{
    __shared__ __align__(16) unsigned short ldsA[2][128 * 32];
    __shared__ __align__(16) unsigned short ldsB[2][128 * 32];

    int i = blockIdx.x;                 // 512 blocks: xcd c owns 8 row-panels
    int c = i & 7, j = i >> 3;
    int bx = j & 7, by = c * 8 + (j >> 3);

    int tid = threadIdx.x;
    int w = tid >> 6, lane = tid & 63;
    int quad = lane >> 4, l15 = lane & 15;
    int wr = w >> 1, wc = w & 1;
    int m0 = by * 128, n0 = bx * 128;

    int crow = tid >> 2, ck = (tid & 3) * 8;

    f4v acc[4][4];
#pragma unroll
    for (int m = 0; m < 4; m++)
#pragma unroll
        for (int n = 0; n < 4; n++) { f4v zz = {0.f, 0.f, 0.f, 0.f}; acc[m][n] = zz; }

    auto stage = [&](int buf, int k0) {
        const unsigned short* ga = A + (size_t)(m0 + crow) * 1024 + k0 + ck;
        GLOAD_LDS(ga, &ldsA[buf][w * 512]);
        GLOAD_LDS(ga + (size_t)64 * 1024, &ldsA[buf][2048 + w * 512]);
        const unsigned short* gb = Bt + (size_t)(n0 + crow) * 1024 + k0 + ck;
        GLOAD_LDS(gb, &ldsB[buf][w * 512]);
        GLOAD_LDS(gb + (size_t)64 * 1024, &ldsB[buf][2048 + w * 512]);
    };

    stage(0, 0);
    __syncthreads();
    for (int t = 0; t < 32; t++) {
        int buf = t & 1;
        if (t < 31) stage(buf ^ 1, (t + 1) * 32);
        s8v af[4], bfr[4];
#pragma unroll
        for (int m = 0; m < 4; m++)
            af[m] = *(const s8v*)&ldsA[buf][(wr * 64 + m * 16 + l15) * 32 + quad * 8];
#pragma unroll
        for (int n = 0; n < 4; n++)
            bfr[n] = *(const s8v*)&ldsB[buf][(wc * 64 + n * 16 + l15) * 32 + quad * 8];
#pragma unroll
        for (int m = 0; m < 4; m++)
#pragma unroll
            for (int n = 0; n < 4; n++)
                acc[m][n] = __builtin_amdgcn_mfma_f32_16x16x32_bf16(af[m], bfr[n], acc[m][n], 0, 0, 0);
        __syncthreads();
    }

#pragma unroll
    for (int n = 0; n < 4; n++) {
        int col = n0 + wc * 64 + n * 16 + l15;
        float bvf = bias[col];
#pragma unroll
        for (int m = 0; m < 4; m++)
#pragma unroll
            for (int r = 0; r < 4; r++) {
                int row = m0 + wr * 64 + m * 16 + quad * 4 + r;
                out[(size_t)row * 1024 + col] = acc[m][n][r] + bvf;
            }
    }
}

// ------- Flash attention (causal), swapped-QK^T, LDS-shared K/V ------------
// (unchanged from round 4 — 89 us, verified)
__global__ __launch_bounds__(256) void attn_kernel(
    const unsigned short* __restrict__ Q,
    const unsigned short* __restrict__ K,
    const unsigned short* __restrict__ Vt,
    unsigned short* __restrict__ O)
{
    __shared__ __align__(16) unsigned short Kb[2][64 * 64];
    __shared__ __align__(16) unsigned short Vb[2][64 * 64];

    int tid = threadIdx.x;
    int w = tid >> 6, lane = tid & 63;
    int quad = lane >> 4, l15 = lane & 15;

    int bid = blockIdx.x;
    int swz = (bid & 7) * 128 + (bid >> 3);
    int xp = swz & 15;
    int h = (swz >> 4) & 15;
    int b = swz >> 8;
    int bh = b * 16 + h;

    int srow = tid >> 3;
    int soff = ((tid & 7) * 16) ^ ((srow & 7) << 4);
    const unsigned short* Kbase = K + (size_t)bh * 2048 * 64;
    const unsigned short* Vbase = Vt + (size_t)bh * 64 * 2048;

    auto stageK = [&](int buf, int kt) {
        const unsigned short* g1 = Kbase + (size_t)(kt * 64 + srow) * 64 + (soff >> 1);
        GLOAD_LDS(g1, &Kb[buf][w * 512]);
        GLOAD_LDS(g1 + (size_t)32 * 64, &Kb[buf][2048 + w * 512]);
    };
    auto stageV = [&](int buf, int kt) {
        const unsigned short* g1 = Vbase + (size_t)srow * 2048 + kt * 64 + (soff >> 1);
        GLOAD_LDS(g1, &Vb[buf][w * 512]);
        GLOAD_LDS(g1 + (size_t)32 * 2048, &Vb[buf][2048 + w * 512]);
    };

    int rswz = (l15 & 7) << 4;

#pragma unroll 1
    for (int half = 0; half < 2; half++) {
        int qt = half ? 31 - xp : xp;
        int m0 = qt * 64 + w * 16;

        const unsigned short* qb = Q + ((size_t)bh * 2048 + m0 + l15) * 64 + quad * 8;
        s8v aq0 = ld8(qb), aq1 = ld8(qb + 32);

        float mrun = -1e30f, lsum = 0.f;
        f4v oacc[4];
#pragma unroll
        for (int t = 0; t < 4; t++) { f4v z = {0.f, 0.f, 0.f, 0.f}; oacc[t] = z; }

        stageK(0, 0);
        stageV(0, 0);
        __syncthreads();

#pragma unroll 1
        for (int kt = 0; kt <= qt; kt++) {
            int buf = kt & 1;
            if (kt < qt) { stageK(buf ^ 1, kt + 1); stageV(buf ^ 1, kt + 1); }

            f4v sacc[4];
#pragma unroll
            for (int t = 0; t < 4; t++) { f4v z = {0.f, 0.f, 0.f, 0.f}; sacc[t] = z; }
            const char* kbp = (const char*)&Kb[buf][0];
#pragma unroll
            for (int t = 0; t < 4; t++) {
                int rb = (t * 16 + l15) * 128;
                s8v k0 = *(const s8v*)(kbp + rb + ((quad * 16) ^ rswz));
                s8v k1 = *(const s8v*)(kbp + rb + ((64 + quad * 16) ^ rswz));
                sacc[t] = __builtin_amdgcn_mfma_f32_16x16x32_bf16(k0, aq0, sacc[t], 0, 0, 0);
                sacc[t] = __builtin_amdgcn_mfma_f32_16x16x32_bf16(k1, aq1, sacc[t], 0, 0, 0);
            }

            if (kt == qt) {
                int qrow = w * 16 + l15;
#pragma unroll
                for (int t = 0; t < 4; t++)
#pragma unroll
                    for (int r = 0; r < 4; r++) {
                        int key = t * 16 + quad * 4 + r;
                        if (key > qrow) sacc[t][r] = -1e30f;
                    }
            }

            float mx = sacc[0][0];
#pragma unroll
            for (int t = 0; t < 4; t++)
#pragma unroll
                for (int r = 0; r < 4; r++)
                    mx = fmaxf(mx, sacc[t][r]);
            mx = fmaxf(mx, __shfl_xor(mx, 16));
            mx = fmaxf(mx, __shfl_xor(mx, 32));

            if (__any(mx > mrun + 8.0f)) {
                float mnew = fmaxf(mrun, mx);
                float alpha = exp2f(mrun - mnew);
                lsum *= alpha;
#pragma unroll
                for (int r = 0; r < 4; r++) {
                    float ar = __shfl(alpha, quad * 4 + r);
#pragma unroll
                    for (int t2 = 0; t2 < 4; t2++) oacc[t2][r] *= ar;
                }
                mrun = mnew;
            }

            float rs = 0.f;
#pragma unroll
            for (int t = 0; t < 4; t++)
#pragma unroll
                for (int r = 0; r < 4; r++) {
                    float p = exp2f(sacc[t][r] - mrun);
                    rs += p;
                    sacc[t][r] = p;
                }
            lsum += rs;

            unsigned int pwv[4][2];
#pragma unroll
            for (int t = 0; t < 4; t++) {
                asm("v_cvt_pk_bf16_f32 %0, %1, %2"
                    : "=v"(pwv[t][0]) : "v"(sacc[t][0]), "v"(sacc[t][1]));
                asm("v_cvt_pk_bf16_f32 %0, %1, %2"
                    : "=v"(pwv[t][1]) : "v"(sacc[t][2]), "v"(sacc[t][3]));
            }

            const char* vbp = (const char*)&Vb[buf][0];
#pragma unroll
            for (int c = 0; c < 2; c++) {
                u4v aw;
                aw[0] = pwv[0][c]; aw[1] = pwv[1][c];
                aw[2] = pwv[2][c]; aw[3] = pwv[3][c];
                s8v apf = __builtin_bit_cast(s8v, aw);
#pragma unroll
                for (int t2 = 0; t2 < 4; t2++) {
                    int rb = (t2 * 16 + l15) * 128;
                    s8v bvv = *(const s8v*)(vbp + rb + ((quad * 32 + c * 16) ^ rswz));
                    oacc[t2] = __builtin_amdgcn_mfma_f32_16x16x32_bf16(apf, bvv, oacc[t2], 0, 0, 0);
                }
            }
            __syncthreads();
        }

        float ltot = lsum;
        ltot += __shfl_xor(ltot, 16);
        ltot += __shfl_xor(ltot, 32);
        float inv = 1.f / ltot;
#pragma unroll
        for (int r = 0; r < 4; r++) {
            float ir = __shfl(inv, quad * 4 + r);
            int l = m0 + quad * 4 + r;
#pragma unroll
            for (int t2 = 0; t2 < 4; t2++) {
                O[((size_t)b * 2048 + l) * 1024 + h * 64 + t2 * 16 + l15] = f2bf(oacc[t2][r] * ir);
            }
        }
    }
}

// ------- launch ------------------------------------------------------------
extern "C" void kernel_launch(void* const* d_in, const int* in_sizes, int n_in,
                              void* d_out, int out_size, void* d_ws, size_t ws_size,
                              hipStream_t stream)
{
    const float* queries = (const float*)d_in[0];
    const float* keys    = (const float*)d_in[1];
    const float* values  = (const float*)d_in[2];
    const float* Wq = (const float*)d_in[3];
    const float* bq = (const float*)d_in[4];
    const float* Wk = (const float*)d_in[5];
    const float* bk = (const float*)d_in[6];
    const float* Wv = (const float*)d_in[7];
    const float* bv = (const float*)d_in[8];
    const float* Wo = (const float*)d_in[9];
    const float* bo = (const float*)d_in[10];

    // ws (bf16 elems): 4x1M W^T + 3x8M Q/K/V^T + 8M ow = 72 MB
    unsigned short* ws = (unsigned short*)d_ws;
    const size_t M1 = 1u << 20, M8 = 8u << 20;
    unsigned short* WqT = ws;
    unsigned short* WkT = ws + 1 * M1;
    unsigned short* WvT = ws + 2 * M1;
    unsigned short* WoT = ws + 3 * M1;
    unsigned short* qw  = ws + 4 * M1;      // [B,H,L,64]
    unsigned short* kw  = qw + M8;          // [B,H,L,64]
    unsigned short* vtw = kw + M8;          // [B,H,64,L] (key-permuted)
    unsigned short* ow  = vtw + M8;         // [B*L,1024]

    const float sscale = 0.125f * LOG2E;

    dim3 tb(32, 8);
    transpose_w4<<<dim3(32, 32, 4), tb, 0, stream>>>(
        Wq, Wk, Wv, Wo, WqT, WkT, WvT, WoT);

    qkv_gemm<<<dim3(1536), 256, 0, stream>>>(
        queries, keys, values, WqT, WkT, WvT, bq, bk, bv,
        qw, kw, vtw, sscale);

    attn_kernel<<<dim3(1024), 256, 0, stream>>>(qw, kw, vtw, ow);

    ogemm<<<dim3(512), 256, 0, stream>>>(ow, WoT, bo, (float*)d_out);
}